// Round 16
// baseline (247.042 us; speedup 1.0000x reference)
//
#include <hip/hip_runtime.h>
#include <math.h>

#define NB 8
#define NC 96
#define HF 64
#define HS 32
#define L 1024
#define MN 1536   // 96 * 16 taps

// workspace layout — regions disjoint during their lifetime:
//  G   (float) : [NB][L][L]   gram                       bytes [0, 32M)
//  F1T (float) : [NB][L][L]   fused+transposed scores    bytes [32M, 64M)
//  YBF (bf16)  : [NB][64][32][64][8]  softmax probs, MFMA-A-fragment order
//  RWTF(bf16)  : [NB][96][32][64][8]  deconv weights, MFMA-B-fragment order
//  N   (float) : [NB][L]      inv patch norms            @104M
//  FS  (float) : [NB][NC][1024] packed f[::2,::2]        @104M+32K
//  BS  (float) : [NB][NC][1024] packed b[::2,::2]        after FS
//  SQP (float) : [NB][96][1024] per-channel bs^2         after BS
//  ZT  (bf16)  : [NB][MN][L]  deconv result TRANSPOSED [m][p], bytes [0, 25.2M)
//                (overlays dead G; 3 MB per n -> L2-resident on its XCD)
#define G_OFF    0ull
#define F1T_OFF  (8ull * 1024 * 1024)           // float offset
#define YB_B     (64ull * 1024 * 1024)          // byte offset
#define RWT_B    (80ull * 1024 * 1024)          // byte offset
#define N_OFF    (27262976ull)                  // float offset (104 MB)
#define FS_OFF   (27271168ull)                  // float offset
#define BS_OFF   (28057600ull)                  // float offset
#define SQP_OFF  (28844032ull)                  // float offset
#define ZT_B     0ull                           // byte offset (bf16 overlay)

typedef __attribute__((ext_vector_type(8))) short short8;
typedef __attribute__((ext_vector_type(4))) float float4v;

__device__ inline unsigned short f2bf(float x) {
    union { float f; unsigned u; } v; v.f = x;
    unsigned r = v.u + 0x7fff + ((v.u >> 16) & 1);   // RNE
    return (unsigned short)(r >> 16);
}
__device__ inline float bf2f(unsigned short h) {
    union { unsigned u; float f; } v; v.u = ((unsigned)h) << 16;
    return v.f;
}

// ---------------------------------------------------------------------------
// KPREP: z=0: stage f plane via LDS (coalesced), pack ::2,::2 -> FS.
//        z=1: stage b plane via LDS, pack -> BS + bs^2 row, emit RWtF
//             (coalesced 1 KB wave stores).
__global__ void kprep(const float* __restrict__ f, const float* __restrict__ b,
                      float* __restrict__ ws) {
    int n = blockIdx.x, c = blockIdx.y, z = blockIdx.z;
    int t = threadIdx.x;
    __shared__ float pl[64][65];
    if (z == 0) {
        const float* src = f + ((size_t)n * NC + c) * (HF * HF);
        for (int e = 0; e < 16; ++e) {
            int idx = t + e * 256;
            pl[idx >> 6][idx & 63] = src[idx];
        }
        __syncthreads();
        float* dst = ws + FS_OFF + ((size_t)n * NC + c) * 1024;
        #pragma unroll
        for (int e = 0; e < 4; ++e) {
            int pos = t + e * 256;
            int i = pos >> 5, j = pos & 31;
            dst[pos] = pl[2 * i][2 * j];
        }
        return;
    }
    const float* bp = b + ((size_t)n * NC + c) * (HF * HF);
    for (int e = 0; e < 16; ++e) {
        int idx = t + e * 256;
        pl[idx >> 6][idx & 63] = bp[idx];
    }
    __syncthreads();
    float* bs = ws + BS_OFF + ((size_t)n * NC + c) * 1024;
    float* sqr = ws + SQP_OFF + ((size_t)n * NC + c) * 1024;
    #pragma unroll
    for (int e = 0; e < 4; ++e) {
        int pos = t + e * 256;
        int i = pos >> 5, j = pos & 31;
        float v = pl[2 * i][2 * j];
        bs[pos] = v;
        sqr[pos] = v * v;
    }
    unsigned short* RWtF = (unsigned short*)((char*)ws + RWT_B) + (size_t)n * MN * L
                           + (size_t)c * 32 * 512;
    int wv = t >> 6, ln = t & 63;
    int qd = ln >> 4, uv = ln & 15;
    int u = uv >> 2, v = uv & 3;
    #pragma unroll
    for (int it = 0; it < 8; ++it) {
        int kc = it * 4 + wv;            // lx = kc
        short8 out8;
        int s = 2 * kc - 1 + v;
        bool sok = (s >= 0 && s < HF);
        #pragma unroll
        for (int j = 0; j < 8; ++j) {
            int ly = qd * 8 + j;
            int r = 2 * ly - 1 + u;
            float val = (sok && r >= 0 && r < HF) ? pl[r][s] : 0.f;
            out8[j] = (short)f2bf(val);
        }
        *(short8*)(RWtF + (size_t)kc * 512 + ln * 8) = out8;
    }
}

// ---------------------------------------------------------------------------
// K1: Gram G[l][p] = sum_c bs[c,l]*fs[c,p].  fp32 128x128 tile, 8x8 micro.
// Grid (8,9,8): y<8 = gram tiles; (y==8, z==0) = inv-norm finalize.
__global__ __launch_bounds__(256) void k1_gram(float* __restrict__ ws) {
    int n = blockIdx.x;
    int t = threadIdx.x;
    if (blockIdx.y == 8) {
        if (blockIdx.z != 0) return;
        __shared__ float sq[1024];
        #pragma unroll
        for (int e = 0; e < 4; ++e) {
            int pos = t + e * 256;
            float s = 0.f;
            for (int c = 0; c < NC; ++c)
                s += ws[SQP_OFF + ((size_t)n * NC + c) * 1024 + pos];
            sq[pos] = s;
        }
        __syncthreads();
        #pragma unroll
        for (int e = 0; e < 4; ++e) {
            int pos = t + e * 256;
            int i = pos >> 5, j = pos & 31;
            float nsq = 0.f;
            #pragma unroll
            for (int dy = -1; dy <= 1; ++dy)
                #pragma unroll
                for (int dx = -1; dx <= 1; ++dx) {
                    int ii = i + dy, jj = j + dx;
                    if (ii >= 0 && ii < HS && jj >= 0 && jj < HS) nsq += sq[ii * HS + jj];
                }
            ws[N_OFF + (size_t)n * L + pos] = 1.f / fmaxf(sqrtf(nsq), 1e-4f);
        }
        return;
    }
    int p0 = blockIdx.y * 128, l0 = blockIdx.z * 128;
    int tp = t >> 4, tm = t & 15;
    __shared__ float Bt[32][132];
    __shared__ float Ft[32][132];
    float acc[8][8] = {};
    const float* bsp = ws + BS_OFF + (size_t)n * NC * 1024;
    const float* fsp = ws + FS_OFF + (size_t)n * NC * 1024;
    for (int c0 = 0; c0 < NC; c0 += 32) {
        #pragma unroll
        for (int e = 0; e < 4; ++e) {
            int idx = t + e * 256;
            int cl = idx >> 5, vq = idx & 31;
            *(float4*)&Bt[cl][vq * 4] =
                *(const float4*)&bsp[(size_t)(c0 + cl) * 1024 + l0 + vq * 4];
            *(float4*)&Ft[cl][vq * 4] =
                *(const float4*)&fsp[(size_t)(c0 + cl) * 1024 + p0 + vq * 4];
        }
        __syncthreads();
        for (int cl = 0; cl < 32; ++cl) {
            float4 a0 = *(const float4*)&Bt[cl][tp * 8];
            float4 a1 = *(const float4*)&Bt[cl][tp * 8 + 4];
            float4 b0 = *(const float4*)&Ft[cl][tm * 8];
            float4 b1 = *(const float4*)&Ft[cl][tm * 8 + 4];
            float av[8] = {a0.x, a0.y, a0.z, a0.w, a1.x, a1.y, a1.z, a1.w};
            float bv[8] = {b0.x, b0.y, b0.z, b0.w, b1.x, b1.y, b1.z, b1.w};
            #pragma unroll
            for (int aa = 0; aa < 8; ++aa)
                #pragma unroll
                for (int bb = 0; bb < 8; ++bb)
                    acc[aa][bb] += av[aa] * bv[bb];
        }
        __syncthreads();
    }
    float* G = ws + G_OFF + (size_t)n * L * L;
    #pragma unroll
    for (int aa = 0; aa < 8; ++aa) {
        int l = l0 + tp * 8 + aa;
        *(float4*)&G[(size_t)l * L + p0 + tm * 8] =
            make_float4(acc[aa][0], acc[aa][1], acc[aa][2], acc[aa][3]);
        *(float4*)&G[(size_t)l * L + p0 + tm * 8 + 4] =
            make_float4(acc[aa][4], acc[aa][5], acc[aa][6], acc[aa][7]);
    }
}

// ---------------------------------------------------------------------------
// K23: fused score + first fuse + transpose, separable taps.
__global__ __launch_bounds__(256) void k23_score_fuse1t(float* __restrict__ ws) {
    int bid = blockIdx.x;            // 8192
    int n = bid & 7;
    int tile = bid >> 3;             // 0..1023
    int i0 = (tile >> 5) * 32, j0 = (tile & 31) * 32;
    int t = threadIdx.x;
    __shared__ float U[36][37];
    __shared__ float sA[34][35];
    __shared__ float sinv[34];
    const float* G = ws + G_OFF + (size_t)n * L * L;
    const float* invn = ws + N_OFF + (size_t)n * L;
    if (t < 34) {
        int l = i0 - 1 + t;
        sinv[t] = ((unsigned)l < L) ? invn[l] : 0.f;
    }
    for (int e = 0; e < 6; ++e) {
        int idx = t + e * 256;       // need 1296
        if (idx < 1296) {
            int a = idx / 36, bq = idx - a * 36;
            int l = i0 - 2 + a, p = j0 - 2 + bq;
            float s = 0.f;
            #pragma unroll
            for (int dy = -1; dy <= 1; ++dy) {
                int ll = l + dy * 32, pp = p + dy * 32;
                if ((unsigned)ll < L && (unsigned)pp < L)
                    s += G[(size_t)ll * L + pp];
            }
            U[a][bq] = s;
        }
    }
    __syncthreads();
    for (int e = 0; e < 5; ++e) {
        int idx = t + e * 256;
        if (idx < 1156) {
            int ih = idx / 34, jh = idx - ih * 34;
            int l = i0 - 1 + ih, p = j0 - 1 + jh;
            float a = 0.f;
            if ((unsigned)l < L && (unsigned)p < L) {
                int lx = l & 31, px = p & 31;
                float s = 0.f;
                #pragma unroll
                for (int dx = -1; dx <= 1; ++dx) {
                    bool ok = (unsigned)(lx + dx) < HS && (unsigned)(px + dx) < HS;
                    float u = U[ih + 1 + dx][jh + 1 + dx];
                    s += ok ? u : 0.f;
                }
                a = sinv[ih] * s;
            }
            sA[ih][jh] = a;
        }
    }
    __syncthreads();
    float* F1T = ws + F1T_OFF + (size_t)n * L * L;
    #pragma unroll
    for (int e = 0; e < 4; ++e) {
        int idx = t + e * 256;
        int jl = idx >> 5, il = idx & 31;
        float v = sA[il][jl] + sA[il + 1][jl + 1] + sA[il + 2][jl + 2];
        F1T[(size_t)(j0 + jl) * L + i0 + il] = v;
    }
}

// ---------------------------------------------------------------------------
// K4 v2: second fuse + softmax, wave-per-p, 4 p's per block.
__global__ __launch_bounds__(256) void k4_fuse2_softmax(float* __restrict__ ws) {
    int n = blockIdx.x, px = blockIdx.y, py0 = blockIdx.z * 4;
    int t = threadIdx.x;
    __shared__ float trow[6][32][33];
    const float* F1T = ws + F1T_OFF + (size_t)n * L * L;
    int Jbase = px * HS + py0;
    #pragma unroll
    for (int e = 0; e < 6; ++e) {
        int idx = t + e * 256;
        int d = idx >> 8, q = idx & 255;
        int Jd = Jbase + d - 1;
        float4 v = make_float4(0.f, 0.f, 0.f, 0.f);
        if ((unsigned)Jd < L) {
            int rd = (Jd & 31) * HS + (Jd >> 5);
            v = *(const float4*)&F1T[(size_t)rd * L + 4 * q];
        }
        int col = q >> 3, r0 = (4 * q) & 31;
        trow[d][r0 + 0][col] = v.x;
        trow[d][r0 + 1][col] = v.y;
        trow[d][r0 + 2][col] = v.z;
        trow[d][r0 + 3][col] = v.w;
    }
    __syncthreads();
    int w = t >> 6, ln = t & 63;
    int py = py0 + w;
    int p = py * HS + px;
    float vals[16];
    float mymax = -1e30f;
    #pragma unroll
    for (int e = 0; e < 16; ++e) {
        int k = e * 64 + ln;
        float v = 0.f;
        #pragma unroll
        for (int d = 0; d < 3; ++d) {
            int kd = k + d - 1;
            if ((unsigned)kd < L) v += trow[w + d][kd >> 5][kd & 31];
        }
        v *= 10.0f;
        vals[e] = v;
        mymax = fmaxf(mymax, v);
    }
    #pragma unroll
    for (int off = 32; off > 0; off >>= 1)
        mymax = fmaxf(mymax, __shfl_xor(mymax, off));
    float mysum = 0.f;
    #pragma unroll
    for (int e = 0; e < 16; ++e) { vals[e] = __expf(vals[e] - mymax); mysum += vals[e]; }
    #pragma unroll
    for (int off = 32; off > 0; off >>= 1)
        mysum += __shfl_xor(mysum, off);
    float rinv = 1.f / mysum;
    unsigned short* YbF = (unsigned short*)((char*)ws + YB_B) + (size_t)n * L * L;
    int pt = p >> 4, fr = p & 15;
    #pragma unroll
    for (int e = 0; e < 16; ++e) {
        int k = e * 64 + ln;
        int kc = k >> 5, qd = (k >> 3) & 3, j = k & 7;
        YbF[((size_t)pt * 32 + kc) * 512 + (qd * 16 + fr) * 8 + j] = f2bf(vals[e] * rinv);
    }
}

// ---------------------------------------------------------------------------
// K6: Z via bf16 MFMA 16x16x32, LDS-free K-loop (frozen r9/r11 config).
// Epilogue v3: bf16 Zt[m][p] assembled in LDS (34 KB) then swept out with
// FULL-LINE coalesced stores — 16 consecutive lanes write 256 contiguous
// bytes (4 full 64 B lines).  r8/r15 bf16 failures were partial-line writes
// (32 B / 8 B segments); this removes them.
__global__ __launch_bounds__(256) void k6_mfma_z(float* __restrict__ ws) {
    int n = blockIdx.x;
    int wv = threadIdx.x >> 6, lane = threadIdx.x & 63;
    int pt0 = blockIdx.z * 8 + (wv >> 1) * 4;
    int mt0 = blockIdx.y * 8 + (wv & 1) * 4;

    const unsigned short* YbF = (const unsigned short*)((const char*)ws + YB_B)
                                + (size_t)n * L * L + lane * 8;
    const unsigned short* RWtF = (const unsigned short*)((const char*)ws + RWT_B)
                                 + (size_t)n * MN * L + lane * 8;

    float4v acc[4][4] = {};
    short8 af[2][4], bf[2][4];
    #pragma unroll
    for (int a = 0; a < 4; ++a) {
        af[0][a] = *(const short8*)(YbF + ((size_t)(pt0 + a) * 32) * 512);
        bf[0][a] = *(const short8*)(RWtF + ((size_t)(mt0 + a) * 32) * 512);
    }
    for (int kc = 0; kc < 32; ++kc) {
        int cur = kc & 1, nxt = cur ^ 1;
        if (kc < 31) {
            #pragma unroll
            for (int a = 0; a < 4; ++a) {
                af[nxt][a] = *(const short8*)(YbF + ((size_t)(pt0 + a) * 32 + kc + 1) * 512);
                bf[nxt][a] = *(const short8*)(RWtF + ((size_t)(mt0 + a) * 32 + kc + 1) * 512);
            }
        }
        #pragma unroll
        for (int a = 0; a < 4; ++a)
            #pragma unroll
            for (int bq = 0; bq < 4; ++bq)
                acc[a][bq] = __builtin_amdgcn_mfma_f32_16x16x32_bf16(
                    af[cur][a], bf[cur][bq], acc[a][bq], 0, 0, 0);
    }

    __shared__ unsigned short zsl[128][136];
    int fr = lane & 15, qd = lane >> 4;
    int pl0 = (wv >> 1) * 64;          // local p base of this wave
    int ml0 = (wv & 1) * 64;           // local m base of this wave
    #pragma unroll
    for (int a = 0; a < 4; ++a) {
        int p_l = pl0 + a * 16 + qd * 4;
        #pragma unroll
        for (int bq = 0; bq < 4; ++bq) {
            int m_l = ml0 + bq * 16 + fr;
            unsigned v0 = (unsigned)f2bf(acc[a][bq][0]) | ((unsigned)f2bf(acc[a][bq][1]) << 16);
            unsigned v1 = (unsigned)f2bf(acc[a][bq][2]) | ((unsigned)f2bf(acc[a][bq][3]) << 16);
            uint2 pk; pk.x = v0; pk.y = v1;
            *(uint2*)&zsl[m_l][p_l] = pk;
        }
    }
    __syncthreads();
    int m0 = blockIdx.y * 128;
    int p0 = blockIdx.z * 128;
    unsigned short* Zt = (unsigned short*)((char*)ws + ZT_B) + (size_t)n * MN * L;
    int t = threadIdx.x;
    #pragma unroll
    for (int e = 0; e < 8; ++e) {
        int idx = t + e * 256;          // 2048 = 128 rows x 16 chunks of 8
        int row = idx >> 4, ch = idx & 15;
        *(short8*)(Zt + (size_t)(m0 + row) * L + p0 + ch * 8) =
            *(const short8*)&zsl[row][ch * 8];
    }
}

// ---------------------------------------------------------------------------
// K7: gather epilogue from transposed bf16 Zt[m][p].  Chunk-major loads:
// 16 consecutive lanes read 256 contiguous bytes per m-row (fully coalesced,
// L2-resident).  Grid (8,16,48): n, yq, cpair.
__global__ __launch_bounds__(256) void k7_gather(const float* __restrict__ ws,
                                                 float* __restrict__ out) {
    int n = blockIdx.x, yq = blockIdx.y, c0 = blockIdx.z * 2;
    int t = threadIdx.x;
    int y0 = yq * 4;
    int ibase = (y0 >> 1) - 1;
    __shared__ float zs[128][33];
    const unsigned short* Zt = (const unsigned short*)((const char*)ws + ZT_B)
                               + (size_t)n * MN * L;
    #pragma unroll
    for (int e = 0; e < 2; ++e) {
        int idx = t + e * 256;          // 512 = 32 m-rows x 16 p-chunks of 8
        int m_l = idx >> 4;             // local m (0..31 over the c-pair)
        int pc = idx & 15;              // chunk — consecutive lanes contiguous
        int il = pc >> 2;
        int i = ibase + il;
        int jb = (pc & 3) * 8;
        short8 v = {};
        if (i >= 0 && i < HS)
            v = *(const short8*)&Zt[(size_t)(c0 * 16 + m_l) * L + i * HS + jb];
        int pbase = il * 32 + jb;
        #pragma unroll
        for (int k = 0; k < 8; ++k)
            zs[pbase + k][m_l] = bf2f((unsigned short)v[k]);
    }
    __syncthreads();
    int y = y0 + (t >> 6), x = t & 63;
    int ih = (y + 1) >> 1, jh = (x + 1) >> 1;
    float s0 = 0.f, s1 = 0.f;
    #pragma unroll
    for (int di = 0; di < 2; ++di) {
        int i = ih - di;
        if (i < 0 || i >= HS) continue;
        int u = y + 1 - 2 * i;
        int il = i - ibase;
        #pragma unroll
        for (int dj = 0; dj < 2; ++dj) {
            int j = jh - dj;
            if (j < 0 || j >= HS) continue;
            int v = x + 1 - 2 * j;
            s0 += zs[il * 32 + j][u * 4 + v];
            s1 += zs[il * 32 + j][16 + u * 4 + v];
        }
    }
    out[(((size_t)n * NC + c0) * HF + y) * HF + x] = 0.25f * s0;
    out[(((size_t)n * NC + c0 + 1) * HF + y) * HF + x] = 0.25f * s1;
}

// ---------------------------------------------------------------------------
extern "C" void kernel_launch(void* const* d_in, const int* in_sizes, int n_in,
                              void* d_out, int out_size, void* d_ws, size_t ws_size,
                              hipStream_t stream) {
    const float* f = (const float*)d_in[0];
    const float* b = (const float*)d_in[1];
    float* out = (float*)d_out;
    float* ws = (float*)d_ws;

    kprep<<<dim3(NB, NC, 2), 256, 0, stream>>>(f, b, ws);
    k1_gram<<<dim3(NB, 9, 8), 256, 0, stream>>>(ws);
    k23_score_fuse1t<<<8192, 256, 0, stream>>>(ws);
    k4_fuse2_softmax<<<dim3(NB, 32, 8), 256, 0, stream>>>(ws);
    k6_mfma_z<<<dim3(NB, 12, 8), 256, 0, stream>>>(ws);
    k7_gather<<<dim3(NB, 16, 48), 256, 0, stream>>>(ws, out);
}

// Round 17
// 194.813 us; speedup vs baseline: 1.2681x; 1.2681x over previous
//
#include <hip/hip_runtime.h>
#include <math.h>

#define NB 8
#define NC 96
#define HF 64
#define HS 32
#define L 1024
#define MN 1536   // 96 * 16 taps

// workspace layout — regions disjoint during their lifetime:
//  G   (float) : [NB][L][L]   gram                       bytes [0, 32M)
//  F1T (float) : [NB][L][L]   fused+transposed scores    bytes [32M, 64M)
//  YBF (bf16)  : [NB][64][32][64][8]  softmax probs, MFMA-A-fragment order
//  RWTF(bf16)  : [NB][96][32][64][8]  deconv weights, MFMA-B-fragment order
//  N   (float) : [NB][L]      inv patch norms            @104M
//  FS  (float) : [NB][NC][1024] packed f[::2,::2]        @104M+32K
//  BS  (float) : [NB][NC][1024] packed b[::2,::2]        after FS
//  SQP (float) : [NB][96][1024] per-channel bs^2         after BS
//  Z   (float) : [NB][L][MN]  deconv matmul result       bytes [0, 50.3M)
//                (overlays G+F1T-prefix, both dead before k6)
// NOTE (r8/r15/r16): bf16 Z regressed three ways (partial-line 2B stores,
// strided 8B stores, LDS-assembled full-line stores -> occupancy loss).
// fp32 Z with full-line stores is the proven optimum for this structure.
#define G_OFF    0ull
#define F1T_OFF  (8ull * 1024 * 1024)           // float offset
#define YB_B     (64ull * 1024 * 1024)          // byte offset
#define RWT_B    (80ull * 1024 * 1024)          // byte offset
#define N_OFF    (27262976ull)                  // float offset (104 MB)
#define FS_OFF   (27271168ull)                  // float offset
#define BS_OFF   (28057600ull)                  // float offset
#define SQP_OFF  (28844032ull)                  // float offset
#define Z_OFF    0ull                           // float offset

typedef __attribute__((ext_vector_type(8))) short short8;
typedef __attribute__((ext_vector_type(4))) float float4v;

__device__ inline unsigned short f2bf(float x) {
    union { float f; unsigned u; } v; v.f = x;
    unsigned r = v.u + 0x7fff + ((v.u >> 16) & 1);   // RNE
    return (unsigned short)(r >> 16);
}

// ---------------------------------------------------------------------------
// KPREP: z=0: stage f plane via LDS (coalesced), pack ::2,::2 -> FS.
//        z=1: stage b plane via LDS, pack -> BS + bs^2 row, emit RWtF
//             (coalesced 1 KB wave stores).
__global__ void kprep(const float* __restrict__ f, const float* __restrict__ b,
                      float* __restrict__ ws) {
    int n = blockIdx.x, c = blockIdx.y, z = blockIdx.z;
    int t = threadIdx.x;
    __shared__ float pl[64][65];
    if (z == 0) {
        const float* src = f + ((size_t)n * NC + c) * (HF * HF);
        for (int e = 0; e < 16; ++e) {
            int idx = t + e * 256;
            pl[idx >> 6][idx & 63] = src[idx];
        }
        __syncthreads();
        float* dst = ws + FS_OFF + ((size_t)n * NC + c) * 1024;
        #pragma unroll
        for (int e = 0; e < 4; ++e) {
            int pos = t + e * 256;
            int i = pos >> 5, j = pos & 31;
            dst[pos] = pl[2 * i][2 * j];
        }
        return;
    }
    const float* bp = b + ((size_t)n * NC + c) * (HF * HF);
    for (int e = 0; e < 16; ++e) {
        int idx = t + e * 256;
        pl[idx >> 6][idx & 63] = bp[idx];
    }
    __syncthreads();
    float* bs = ws + BS_OFF + ((size_t)n * NC + c) * 1024;
    float* sqr = ws + SQP_OFF + ((size_t)n * NC + c) * 1024;
    #pragma unroll
    for (int e = 0; e < 4; ++e) {
        int pos = t + e * 256;
        int i = pos >> 5, j = pos & 31;
        float v = pl[2 * i][2 * j];
        bs[pos] = v;
        sqr[pos] = v * v;
    }
    unsigned short* RWtF = (unsigned short*)((char*)ws + RWT_B) + (size_t)n * MN * L
                           + (size_t)c * 32 * 512;
    int wv = t >> 6, ln = t & 63;
    int qd = ln >> 4, uv = ln & 15;
    int u = uv >> 2, v = uv & 3;
    #pragma unroll
    for (int it = 0; it < 8; ++it) {
        int kc = it * 4 + wv;            // lx = kc
        short8 out8;
        int s = 2 * kc - 1 + v;
        bool sok = (s >= 0 && s < HF);
        #pragma unroll
        for (int j = 0; j < 8; ++j) {
            int ly = qd * 8 + j;
            int r = 2 * ly - 1 + u;
            float val = (sok && r >= 0 && r < HF) ? pl[r][s] : 0.f;
            out8[j] = (short)f2bf(val);
        }
        *(short8*)(RWtF + (size_t)kc * 512 + ln * 8) = out8;
    }
}

// ---------------------------------------------------------------------------
// K1: Gram G[l][p] = sum_c bs[c,l]*fs[c,p].  fp32 128x128 tile, 8x8 micro.
// Grid (8,9,8): y<8 = normal gram tiles; (y==8, z==0) = inv-norm finalize
// (absorbs old k0b — sums 96 SQP rows, 3x3 neighborhood, writes N).
__global__ __launch_bounds__(256) void k1_gram(float* __restrict__ ws) {
    int n = blockIdx.x;
    int t = threadIdx.x;
    if (blockIdx.y == 8) {
        if (blockIdx.z != 0) return;
        __shared__ float sq[1024];
        #pragma unroll
        for (int e = 0; e < 4; ++e) {
            int pos = t + e * 256;
            float s = 0.f;
            for (int c = 0; c < NC; ++c)
                s += ws[SQP_OFF + ((size_t)n * NC + c) * 1024 + pos];
            sq[pos] = s;
        }
        __syncthreads();
        #pragma unroll
        for (int e = 0; e < 4; ++e) {
            int pos = t + e * 256;
            int i = pos >> 5, j = pos & 31;
            float nsq = 0.f;
            #pragma unroll
            for (int dy = -1; dy <= 1; ++dy)
                #pragma unroll
                for (int dx = -1; dx <= 1; ++dx) {
                    int ii = i + dy, jj = j + dx;
                    if (ii >= 0 && ii < HS && jj >= 0 && jj < HS) nsq += sq[ii * HS + jj];
                }
            ws[N_OFF + (size_t)n * L + pos] = 1.f / fmaxf(sqrtf(nsq), 1e-4f);
        }
        return;
    }
    int p0 = blockIdx.y * 128, l0 = blockIdx.z * 128;
    int tp = t >> 4, tm = t & 15;
    __shared__ float Bt[32][132];
    __shared__ float Ft[32][132];
    float acc[8][8] = {};
    const float* bsp = ws + BS_OFF + (size_t)n * NC * 1024;
    const float* fsp = ws + FS_OFF + (size_t)n * NC * 1024;
    for (int c0 = 0; c0 < NC; c0 += 32) {
        #pragma unroll
        for (int e = 0; e < 4; ++e) {
            int idx = t + e * 256;
            int cl = idx >> 5, vq = idx & 31;
            *(float4*)&Bt[cl][vq * 4] =
                *(const float4*)&bsp[(size_t)(c0 + cl) * 1024 + l0 + vq * 4];
            *(float4*)&Ft[cl][vq * 4] =
                *(const float4*)&fsp[(size_t)(c0 + cl) * 1024 + p0 + vq * 4];
        }
        __syncthreads();
        for (int cl = 0; cl < 32; ++cl) {
            float4 a0 = *(const float4*)&Bt[cl][tp * 8];
            float4 a1 = *(const float4*)&Bt[cl][tp * 8 + 4];
            float4 b0 = *(const float4*)&Ft[cl][tm * 8];
            float4 b1 = *(const float4*)&Ft[cl][tm * 8 + 4];
            float av[8] = {a0.x, a0.y, a0.z, a0.w, a1.x, a1.y, a1.z, a1.w};
            float bv[8] = {b0.x, b0.y, b0.z, b0.w, b1.x, b1.y, b1.z, b1.w};
            #pragma unroll
            for (int aa = 0; aa < 8; ++aa)
                #pragma unroll
                for (int bb = 0; bb < 8; ++bb)
                    acc[aa][bb] += av[aa] * bv[bb];
        }
        __syncthreads();
    }
    float* G = ws + G_OFF + (size_t)n * L * L;
    #pragma unroll
    for (int aa = 0; aa < 8; ++aa) {
        int l = l0 + tp * 8 + aa;
        *(float4*)&G[(size_t)l * L + p0 + tm * 8] =
            make_float4(acc[aa][0], acc[aa][1], acc[aa][2], acc[aa][3]);
        *(float4*)&G[(size_t)l * L + p0 + tm * 8 + 4] =
            make_float4(acc[aa][4], acc[aa][5], acc[aa][6], acc[aa][7]);
    }
}

// ---------------------------------------------------------------------------
// K23: fused score + first fuse + transpose, separable taps.
__global__ __launch_bounds__(256) void k23_score_fuse1t(float* __restrict__ ws) {
    int bid = blockIdx.x;            // 8192
    int n = bid & 7;
    int tile = bid >> 3;             // 0..1023
    int i0 = (tile >> 5) * 32, j0 = (tile & 31) * 32;
    int t = threadIdx.x;
    __shared__ float U[36][37];
    __shared__ float sA[34][35];
    __shared__ float sinv[34];
    const float* G = ws + G_OFF + (size_t)n * L * L;
    const float* invn = ws + N_OFF + (size_t)n * L;
    if (t < 34) {
        int l = i0 - 1 + t;
        sinv[t] = ((unsigned)l < L) ? invn[l] : 0.f;
    }
    for (int e = 0; e < 6; ++e) {
        int idx = t + e * 256;       // need 1296
        if (idx < 1296) {
            int a = idx / 36, bq = idx - a * 36;
            int l = i0 - 2 + a, p = j0 - 2 + bq;
            float s = 0.f;
            #pragma unroll
            for (int dy = -1; dy <= 1; ++dy) {
                int ll = l + dy * 32, pp = p + dy * 32;
                if ((unsigned)ll < L && (unsigned)pp < L)
                    s += G[(size_t)ll * L + pp];
            }
            U[a][bq] = s;
        }
    }
    __syncthreads();
    for (int e = 0; e < 5; ++e) {
        int idx = t + e * 256;
        if (idx < 1156) {
            int ih = idx / 34, jh = idx - ih * 34;
            int l = i0 - 1 + ih, p = j0 - 1 + jh;
            float a = 0.f;
            if ((unsigned)l < L && (unsigned)p < L) {
                int lx = l & 31, px = p & 31;
                float s = 0.f;
                #pragma unroll
                for (int dx = -1; dx <= 1; ++dx) {
                    bool ok = (unsigned)(lx + dx) < HS && (unsigned)(px + dx) < HS;
                    float u = U[ih + 1 + dx][jh + 1 + dx];
                    s += ok ? u : 0.f;
                }
                a = sinv[ih] * s;
            }
            sA[ih][jh] = a;
        }
    }
    __syncthreads();
    float* F1T = ws + F1T_OFF + (size_t)n * L * L;
    #pragma unroll
    for (int e = 0; e < 4; ++e) {
        int idx = t + e * 256;
        int jl = idx >> 5, il = idx & 31;
        float v = sA[il][jl] + sA[il + 1][jl + 1] + sA[il + 2][jl + 2];
        F1T[(size_t)(j0 + jl) * L + i0 + il] = v;
    }
}

// ---------------------------------------------------------------------------
// K4 v2: second fuse + softmax, wave-per-p, 4 p's per block.
__global__ __launch_bounds__(256) void k4_fuse2_softmax(float* __restrict__ ws) {
    int n = blockIdx.x, px = blockIdx.y, py0 = blockIdx.z * 4;
    int t = threadIdx.x;
    __shared__ float trow[6][32][33];
    const float* F1T = ws + F1T_OFF + (size_t)n * L * L;
    int Jbase = px * HS + py0;
    #pragma unroll
    for (int e = 0; e < 6; ++e) {
        int idx = t + e * 256;
        int d = idx >> 8, q = idx & 255;
        int Jd = Jbase + d - 1;
        float4 v = make_float4(0.f, 0.f, 0.f, 0.f);
        if ((unsigned)Jd < L) {
            int rd = (Jd & 31) * HS + (Jd >> 5);
            v = *(const float4*)&F1T[(size_t)rd * L + 4 * q];
        }
        int col = q >> 3, r0 = (4 * q) & 31;
        trow[d][r0 + 0][col] = v.x;
        trow[d][r0 + 1][col] = v.y;
        trow[d][r0 + 2][col] = v.z;
        trow[d][r0 + 3][col] = v.w;
    }
    __syncthreads();
    int w = t >> 6, ln = t & 63;
    int py = py0 + w;
    int p = py * HS + px;
    float vals[16];
    float mymax = -1e30f;
    #pragma unroll
    for (int e = 0; e < 16; ++e) {
        int k = e * 64 + ln;
        float v = 0.f;
        #pragma unroll
        for (int d = 0; d < 3; ++d) {
            int kd = k + d - 1;
            if ((unsigned)kd < L) v += trow[w + d][kd >> 5][kd & 31];
        }
        v *= 10.0f;
        vals[e] = v;
        mymax = fmaxf(mymax, v);
    }
    #pragma unroll
    for (int off = 32; off > 0; off >>= 1)
        mymax = fmaxf(mymax, __shfl_xor(mymax, off));
    float mysum = 0.f;
    #pragma unroll
    for (int e = 0; e < 16; ++e) { vals[e] = __expf(vals[e] - mymax); mysum += vals[e]; }
    #pragma unroll
    for (int off = 32; off > 0; off >>= 1)
        mysum += __shfl_xor(mysum, off);
    float rinv = 1.f / mysum;
    unsigned short* YbF = (unsigned short*)((char*)ws + YB_B) + (size_t)n * L * L;
    int pt = p >> 4, fr = p & 15;
    #pragma unroll
    for (int e = 0; e < 16; ++e) {
        int k = e * 64 + ln;
        int kc = k >> 5, qd = (k >> 3) & 3, j = k & 7;
        YbF[((size_t)pt * 32 + kc) * 512 + (qd * 16 + fr) * 8 + j] = f2bf(vals[e] * rinv);
    }
}

// ---------------------------------------------------------------------------
// K6: Z[p][m] = sum_k Yb[p][k]*RWt[m][k] via bf16 MFMA 16x16x32.  LDS-free,
// barrier-free, fragment-order operands, register double-buffer.
// r9/r11-proven config (grid (8,12,8), 128x128 tile, 4x4 wave) — frozen:
// retiles (r10, r12) and bf16-Z epilogues (r8, r15, r16) all regressed.
__global__ __launch_bounds__(256) void k6_mfma_z(float* __restrict__ ws) {
    int n = blockIdx.x;
    int wv = threadIdx.x >> 6, lane = threadIdx.x & 63;
    int pt0 = blockIdx.z * 8 + (wv >> 1) * 4;
    int mt0 = blockIdx.y * 8 + (wv & 1) * 4;

    const unsigned short* YbF = (const unsigned short*)((const char*)ws + YB_B)
                                + (size_t)n * L * L + lane * 8;
    const unsigned short* RWtF = (const unsigned short*)((const char*)ws + RWT_B)
                                 + (size_t)n * MN * L + lane * 8;

    float4v acc[4][4] = {};
    short8 af[2][4], bf[2][4];
    #pragma unroll
    for (int a = 0; a < 4; ++a) {
        af[0][a] = *(const short8*)(YbF + ((size_t)(pt0 + a) * 32) * 512);
        bf[0][a] = *(const short8*)(RWtF + ((size_t)(mt0 + a) * 32) * 512);
    }
    for (int kc = 0; kc < 32; ++kc) {
        int cur = kc & 1, nxt = cur ^ 1;
        if (kc < 31) {
            #pragma unroll
            for (int a = 0; a < 4; ++a) {
                af[nxt][a] = *(const short8*)(YbF + ((size_t)(pt0 + a) * 32 + kc + 1) * 512);
                bf[nxt][a] = *(const short8*)(RWtF + ((size_t)(mt0 + a) * 32 + kc + 1) * 512);
            }
        }
        #pragma unroll
        for (int a = 0; a < 4; ++a)
            #pragma unroll
            for (int bq = 0; bq < 4; ++bq)
                acc[a][bq] = __builtin_amdgcn_mfma_f32_16x16x32_bf16(
                    af[cur][a], bf[cur][bq], acc[a][bq], 0, 0, 0);
    }

    int fr = lane & 15, qd = lane >> 4;
    float* Zp = ws + Z_OFF + (size_t)n * L * MN;
    #pragma unroll
    for (int a = 0; a < 4; ++a) {
        #pragma unroll
        for (int r = 0; r < 4; ++r) {
            int p = (pt0 + a) * 16 + qd * 4 + r;
            #pragma unroll
            for (int bq = 0; bq < 4; ++bq) {
                int m = (mt0 + bq) * 16 + fr;
                Zp[(size_t)p * MN + m] = acc[a][bq][r];
            }
        }
    }
}

// ---------------------------------------------------------------------------
// K7: gather epilogue, 2 c-planes per block.  Grid (8,16,48).
__global__ __launch_bounds__(256) void k7_gather(const float* __restrict__ ws,
                                                 float* __restrict__ out) {
    int n = blockIdx.x, yq = blockIdx.y, c0 = blockIdx.z * 2;
    int t = threadIdx.x;
    int y0 = yq * 4;
    int ibase = (y0 >> 1) - 1;
    __shared__ float zs[128][33];
    const float* Zp = ws + Z_OFF + (size_t)n * L * MN;
    #pragma unroll
    for (int e = 0; e < 4; ++e) {
        int idx = t + e * 256;          // 1024 = 128 pl x 8 float4-chunks
        int pl = idx >> 3, q = idx & 7;
        int il = pl >> 5, j = pl & 31;
        int i = ibase + il;
        float4 v = make_float4(0.f, 0.f, 0.f, 0.f);
        if (i >= 0 && i < HS)
            v = *(const float4*)&Zp[(size_t)(i * HS + j) * MN + c0 * 16 + q * 4];
        zs[pl][q * 4 + 0] = v.x;
        zs[pl][q * 4 + 1] = v.y;
        zs[pl][q * 4 + 2] = v.z;
        zs[pl][q * 4 + 3] = v.w;
    }
    __syncthreads();
    int y = y0 + (t >> 6), x = t & 63;
    int ih = (y + 1) >> 1, jh = (x + 1) >> 1;
    float s0 = 0.f, s1 = 0.f;
    #pragma unroll
    for (int di = 0; di < 2; ++di) {
        int i = ih - di;
        if (i < 0 || i >= HS) continue;
        int u = y + 1 - 2 * i;
        int il = i - ibase;
        #pragma unroll
        for (int dj = 0; dj < 2; ++dj) {
            int j = jh - dj;
            if (j < 0 || j >= HS) continue;
            int v = x + 1 - 2 * j;
            s0 += zs[il * 32 + j][u * 4 + v];
            s1 += zs[il * 32 + j][16 + u * 4 + v];
        }
    }
    out[(((size_t)n * NC + c0) * HF + y) * HF + x] = 0.25f * s0;
    out[(((size_t)n * NC + c0 + 1) * HF + y) * HF + x] = 0.25f * s1;
}

// ---------------------------------------------------------------------------
extern "C" void kernel_launch(void* const* d_in, const int* in_sizes, int n_in,
                              void* d_out, int out_size, void* d_ws, size_t ws_size,
                              hipStream_t stream) {
    const float* f = (const float*)d_in[0];
    const float* b = (const float*)d_in[1];
    float* out = (float*)d_out;
    float* ws = (float*)d_ws;

    kprep<<<dim3(NB, NC, 2), 256, 0, stream>>>(f, b, ws);
    k1_gram<<<dim3(NB, 9, 8), 256, 0, stream>>>(ws);
    k23_score_fuse1t<<<8192, 256, 0, stream>>>(ws);
    k4_fuse2_softmax<<<dim3(NB, 32, 8), 256, 0, stream>>>(ws);
    k6_mfma_z<<<dim3(NB, 12, 8), 256, 0, stream>>>(ws);
    k7_gather<<<dim3(NB, 16, 48), 256, 0, stream>>>(ws, out);
}

// Round 18
// 191.053 us; speedup vs baseline: 1.2930x; 1.0197x over previous
//
#include <hip/hip_runtime.h>
#include <math.h>

#define NB 8
#define NC 96
#define HF 64
#define HS 32
#define L 1024
#define MN 1536   // 96 * 16 taps

// workspace layout — regions disjoint during their lifetime:
//  G   (float) : [NB][L][L]   gram                       bytes [0, 32M)
//  F1T (float) : [NB][L][L]   fused+transposed scores    bytes [32M, 64M)
//  YBF (bf16)  : [NB][64][32][64][8]  softmax probs, MFMA-A-fragment order
//  RWTF(bf16)  : [NB][96][32][64][8]  deconv weights, MFMA-B-fragment order
//  N   (float) : [NB][L]      inv patch norms            @104M
//  FS  (float) : [NB][NC][1024] packed f[::2,::2]        @104M+32K
//  BS  (float) : [NB][NC][1024] packed b[::2,::2]        after FS
//  SQP (float) : [NB][96][1024] per-channel bs^2         after BS
//  Z   (float) : [NB][L][MN]  deconv matmul result       bytes [0, 50.3M)
// NOTE (r8/r15/r16): bf16 Z closed (3 mechanisms).  fp32 Z + full-line
// stores is the proven optimum.  k6 tiling frozen (r10/r12 saddle).
#define G_OFF    0ull
#define F1T_OFF  (8ull * 1024 * 1024)           // float offset
#define YB_B     (64ull * 1024 * 1024)          // byte offset
#define RWT_B    (80ull * 1024 * 1024)          // byte offset
#define N_OFF    (27262976ull)                  // float offset (104 MB)
#define FS_OFF   (27271168ull)                  // float offset
#define BS_OFF   (28057600ull)                  // float offset
#define SQP_OFF  (28844032ull)                  // float offset
#define Z_OFF    0ull                           // float offset

typedef __attribute__((ext_vector_type(8))) short short8;
typedef __attribute__((ext_vector_type(4))) float float4v;

__device__ inline unsigned short f2bf(float x) {
    union { float f; unsigned u; } v; v.f = x;
    unsigned r = v.u + 0x7fff + ((v.u >> 16) & 1);   // RNE
    return (unsigned short)(r >> 16);
}

// ---------------------------------------------------------------------------
// KPREP: z=0: stage f plane via LDS (coalesced), pack ::2,::2 -> FS.
//        z=1: stage b plane via LDS, pack -> BS + bs^2 row, emit RWtF
//             (coalesced 1 KB wave stores).
__global__ void kprep(const float* __restrict__ f, const float* __restrict__ b,
                      float* __restrict__ ws) {
    int n = blockIdx.x, c = blockIdx.y, z = blockIdx.z;
    int t = threadIdx.x;
    __shared__ float pl[64][65];
    if (z == 0) {
        const float* src = f + ((size_t)n * NC + c) * (HF * HF);
        for (int e = 0; e < 16; ++e) {
            int idx = t + e * 256;
            pl[idx >> 6][idx & 63] = src[idx];
        }
        __syncthreads();
        float* dst = ws + FS_OFF + ((size_t)n * NC + c) * 1024;
        #pragma unroll
        for (int e = 0; e < 4; ++e) {
            int pos = t + e * 256;
            int i = pos >> 5, j = pos & 31;
            dst[pos] = pl[2 * i][2 * j];
        }
        return;
    }
    const float* bp = b + ((size_t)n * NC + c) * (HF * HF);
    for (int e = 0; e < 16; ++e) {
        int idx = t + e * 256;
        pl[idx >> 6][idx & 63] = bp[idx];
    }
    __syncthreads();
    float* bs = ws + BS_OFF + ((size_t)n * NC + c) * 1024;
    float* sqr = ws + SQP_OFF + ((size_t)n * NC + c) * 1024;
    #pragma unroll
    for (int e = 0; e < 4; ++e) {
        int pos = t + e * 256;
        int i = pos >> 5, j = pos & 31;
        float v = pl[2 * i][2 * j];
        bs[pos] = v;
        sqr[pos] = v * v;
    }
    unsigned short* RWtF = (unsigned short*)((char*)ws + RWT_B) + (size_t)n * MN * L
                           + (size_t)c * 32 * 512;
    int wv = t >> 6, ln = t & 63;
    int qd = ln >> 4, uv = ln & 15;
    int u = uv >> 2, v = uv & 3;
    #pragma unroll
    for (int it = 0; it < 8; ++it) {
        int kc = it * 4 + wv;            // lx = kc
        short8 out8;
        int s = 2 * kc - 1 + v;
        bool sok = (s >= 0 && s < HF);
        #pragma unroll
        for (int j = 0; j < 8; ++j) {
            int ly = qd * 8 + j;
            int r = 2 * ly - 1 + u;
            float val = (sok && r >= 0 && r < HF) ? pl[r][s] : 0.f;
            out8[j] = (short)f2bf(val);
        }
        *(short8*)(RWtF + (size_t)kc * 512 + ln * 8) = out8;
    }
}

// ---------------------------------------------------------------------------
// K1: Gram G[l][p] = sum_c bs[c,l]*fs[c,p].  fp32 128x128 tile, 8x8 micro.
// Grid (8,9,8): y<8 = gram tiles; (y==8, z==0) = inv-norm finalize.
__global__ __launch_bounds__(256) void k1_gram(float* __restrict__ ws) {
    int n = blockIdx.x;
    int t = threadIdx.x;
    if (blockIdx.y == 8) {
        if (blockIdx.z != 0) return;
        __shared__ float sq[1024];
        #pragma unroll
        for (int e = 0; e < 4; ++e) {
            int pos = t + e * 256;
            float s = 0.f;
            for (int c = 0; c < NC; ++c)
                s += ws[SQP_OFF + ((size_t)n * NC + c) * 1024 + pos];
            sq[pos] = s;
        }
        __syncthreads();
        #pragma unroll
        for (int e = 0; e < 4; ++e) {
            int pos = t + e * 256;
            int i = pos >> 5, j = pos & 31;
            float nsq = 0.f;
            #pragma unroll
            for (int dy = -1; dy <= 1; ++dy)
                #pragma unroll
                for (int dx = -1; dx <= 1; ++dx) {
                    int ii = i + dy, jj = j + dx;
                    if (ii >= 0 && ii < HS && jj >= 0 && jj < HS) nsq += sq[ii * HS + jj];
                }
            ws[N_OFF + (size_t)n * L + pos] = 1.f / fmaxf(sqrtf(nsq), 1e-4f);
        }
        return;
    }
    int p0 = blockIdx.y * 128, l0 = blockIdx.z * 128;
    int tp = t >> 4, tm = t & 15;
    __shared__ float Bt[32][132];
    __shared__ float Ft[32][132];
    float acc[8][8] = {};
    const float* bsp = ws + BS_OFF + (size_t)n * NC * 1024;
    const float* fsp = ws + FS_OFF + (size_t)n * NC * 1024;
    for (int c0 = 0; c0 < NC; c0 += 32) {
        #pragma unroll
        for (int e = 0; e < 4; ++e) {
            int idx = t + e * 256;
            int cl = idx >> 5, vq = idx & 31;
            *(float4*)&Bt[cl][vq * 4] =
                *(const float4*)&bsp[(size_t)(c0 + cl) * 1024 + l0 + vq * 4];
            *(float4*)&Ft[cl][vq * 4] =
                *(const float4*)&fsp[(size_t)(c0 + cl) * 1024 + p0 + vq * 4];
        }
        __syncthreads();
        for (int cl = 0; cl < 32; ++cl) {
            float4 a0 = *(const float4*)&Bt[cl][tp * 8];
            float4 a1 = *(const float4*)&Bt[cl][tp * 8 + 4];
            float4 b0 = *(const float4*)&Ft[cl][tm * 8];
            float4 b1 = *(const float4*)&Ft[cl][tm * 8 + 4];
            float av[8] = {a0.x, a0.y, a0.z, a0.w, a1.x, a1.y, a1.z, a1.w};
            float bv[8] = {b0.x, b0.y, b0.z, b0.w, b1.x, b1.y, b1.z, b1.w};
            #pragma unroll
            for (int aa = 0; aa < 8; ++aa)
                #pragma unroll
                for (int bb = 0; bb < 8; ++bb)
                    acc[aa][bb] += av[aa] * bv[bb];
        }
        __syncthreads();
    }
    float* G = ws + G_OFF + (size_t)n * L * L;
    #pragma unroll
    for (int aa = 0; aa < 8; ++aa) {
        int l = l0 + tp * 8 + aa;
        *(float4*)&G[(size_t)l * L + p0 + tm * 8] =
            make_float4(acc[aa][0], acc[aa][1], acc[aa][2], acc[aa][3]);
        *(float4*)&G[(size_t)l * L + p0 + tm * 8 + 4] =
            make_float4(acc[aa][4], acc[aa][5], acc[aa][6], acc[aa][7]);
    }
}

// ---------------------------------------------------------------------------
// K23 v4: fused score + first fuse + transpose, separable taps, WIDE tiles
// 32(i) x 64(j): half the blocks/barriers of the 32x32 version, j-halo
// overhead 1.125 -> 1.06.  LDS ~19 KB -> still 8 blocks/CU.
// Arithmetic per output element is bit-identical to r17.
__global__ __launch_bounds__(256) void k23_score_fuse1t(float* __restrict__ ws) {
    int bid = blockIdx.x;            // 4096
    int n = bid & 7;
    int tile = bid >> 3;             // 0..511 = 32 i-tiles x 16 j-tiles
    int i0 = (tile >> 4) * 32, j0 = (tile & 15) * 64;
    int t = threadIdx.x;
    __shared__ float U[36][69];
    __shared__ float sA[34][67];
    __shared__ float sinv[34];
    const float* G = ws + G_OFF + (size_t)n * L * L;
    const float* invn = ws + N_OFF + (size_t)n * L;
    if (t < 34) {
        int l = i0 - 1 + t;
        sinv[t] = ((unsigned)l < L) ? invn[l] : 0.f;
    }
    for (int e = 0; e < 10; ++e) {
        int idx = t + e * 256;       // need 36*68 = 2448
        if (idx < 2448) {
            int a = idx / 68, bq = idx - a * 68;
            int l = i0 - 2 + a, p = j0 - 2 + bq;
            float s = 0.f;
            #pragma unroll
            for (int dy = -1; dy <= 1; ++dy) {
                int ll = l + dy * 32, pp = p + dy * 32;
                if ((unsigned)ll < L && (unsigned)pp < L)
                    s += G[(size_t)ll * L + pp];
            }
            U[a][bq] = s;
        }
    }
    __syncthreads();
    for (int e = 0; e < 9; ++e) {
        int idx = t + e * 256;       // need 34*66 = 2244
        if (idx < 2244) {
            int ih = idx / 66, jh = idx - ih * 66;
            int l = i0 - 1 + ih, p = j0 - 1 + jh;
            float a = 0.f;
            if ((unsigned)l < L && (unsigned)p < L) {
                int lx = l & 31, px = p & 31;
                float s = 0.f;
                #pragma unroll
                for (int dx = -1; dx <= 1; ++dx) {
                    bool ok = (unsigned)(lx + dx) < HS && (unsigned)(px + dx) < HS;
                    float u = U[ih + 1 + dx][jh + 1 + dx];
                    s += ok ? u : 0.f;
                }
                a = sinv[ih] * s;
            }
            sA[ih][jh] = a;
        }
    }
    __syncthreads();
    float* F1T = ws + F1T_OFF + (size_t)n * L * L;
    #pragma unroll
    for (int e = 0; e < 8; ++e) {
        int idx = t + e * 256;       // 2048 = 64 jl x 32 il
        int jl = idx >> 5, il = idx & 31;
        float v = sA[il][jl] + sA[il + 1][jl + 1] + sA[il + 2][jl + 2];
        F1T[(size_t)(j0 + jl) * L + i0 + il] = v;
    }
}

// ---------------------------------------------------------------------------
// K4 v2: second fuse + softmax, wave-per-p, 4 p's per block.
__global__ __launch_bounds__(256) void k4_fuse2_softmax(float* __restrict__ ws) {
    int n = blockIdx.x, px = blockIdx.y, py0 = blockIdx.z * 4;
    int t = threadIdx.x;
    __shared__ float trow[6][32][33];
    const float* F1T = ws + F1T_OFF + (size_t)n * L * L;
    int Jbase = px * HS + py0;
    #pragma unroll
    for (int e = 0; e < 6; ++e) {
        int idx = t + e * 256;
        int d = idx >> 8, q = idx & 255;
        int Jd = Jbase + d - 1;
        float4 v = make_float4(0.f, 0.f, 0.f, 0.f);
        if ((unsigned)Jd < L) {
            int rd = (Jd & 31) * HS + (Jd >> 5);
            v = *(const float4*)&F1T[(size_t)rd * L + 4 * q];
        }
        int col = q >> 3, r0 = (4 * q) & 31;
        trow[d][r0 + 0][col] = v.x;
        trow[d][r0 + 1][col] = v.y;
        trow[d][r0 + 2][col] = v.z;
        trow[d][r0 + 3][col] = v.w;
    }
    __syncthreads();
    int w = t >> 6, ln = t & 63;
    int py = py0 + w;
    int p = py * HS + px;
    float vals[16];
    float mymax = -1e30f;
    #pragma unroll
    for (int e = 0; e < 16; ++e) {
        int k = e * 64 + ln;
        float v = 0.f;
        #pragma unroll
        for (int d = 0; d < 3; ++d) {
            int kd = k + d - 1;
            if ((unsigned)kd < L) v += trow[w + d][kd >> 5][kd & 31];
        }
        v *= 10.0f;
        vals[e] = v;
        mymax = fmaxf(mymax, v);
    }
    #pragma unroll
    for (int off = 32; off > 0; off >>= 1)
        mymax = fmaxf(mymax, __shfl_xor(mymax, off));
    float mysum = 0.f;
    #pragma unroll
    for (int e = 0; e < 16; ++e) { vals[e] = __expf(vals[e] - mymax); mysum += vals[e]; }
    #pragma unroll
    for (int off = 32; off > 0; off >>= 1)
        mysum += __shfl_xor(mysum, off);
    float rinv = 1.f / mysum;
    unsigned short* YbF = (unsigned short*)((char*)ws + YB_B) + (size_t)n * L * L;
    int pt = p >> 4, fr = p & 15;
    #pragma unroll
    for (int e = 0; e < 16; ++e) {
        int k = e * 64 + ln;
        int kc = k >> 5, qd = (k >> 3) & 3, j = k & 7;
        YbF[((size_t)pt * 32 + kc) * 512 + (qd * 16 + fr) * 8 + j] = f2bf(vals[e] * rinv);
    }
}

// ---------------------------------------------------------------------------
// K6: Z[p][m] = sum_k Yb[p][k]*RWt[m][k] via bf16 MFMA 16x16x32.  LDS-free,
// barrier-free, fragment-order operands, register double-buffer.  Frozen.
__global__ __launch_bounds__(256) void k6_mfma_z(float* __restrict__ ws) {
    int n = blockIdx.x;
    int wv = threadIdx.x >> 6, lane = threadIdx.x & 63;
    int pt0 = blockIdx.z * 8 + (wv >> 1) * 4;
    int mt0 = blockIdx.y * 8 + (wv & 1) * 4;

    const unsigned short* YbF = (const unsigned short*)((const char*)ws + YB_B)
                                + (size_t)n * L * L + lane * 8;
    const unsigned short* RWtF = (const unsigned short*)((const char*)ws + RWT_B)
                                 + (size_t)n * MN * L + lane * 8;

    float4v acc[4][4] = {};
    short8 af[2][4], bf[2][4];
    #pragma unroll
    for (int a = 0; a < 4; ++a) {
        af[0][a] = *(const short8*)(YbF + ((size_t)(pt0 + a) * 32) * 512);
        bf[0][a] = *(const short8*)(RWtF + ((size_t)(mt0 + a) * 32) * 512);
    }
    for (int kc = 0; kc < 32; ++kc) {
        int cur = kc & 1, nxt = cur ^ 1;
        if (kc < 31) {
            #pragma unroll
            for (int a = 0; a < 4; ++a) {
                af[nxt][a] = *(const short8*)(YbF + ((size_t)(pt0 + a) * 32 + kc + 1) * 512);
                bf[nxt][a] = *(const short8*)(RWtF + ((size_t)(mt0 + a) * 32 + kc + 1) * 512);
            }
        }
        #pragma unroll
        for (int a = 0; a < 4; ++a)
            #pragma unroll
            for (int bq = 0; bq < 4; ++bq)
                acc[a][bq] = __builtin_amdgcn_mfma_f32_16x16x32_bf16(
                    af[cur][a], bf[cur][bq], acc[a][bq], 0, 0, 0);
    }

    int fr = lane & 15, qd = lane >> 4;
    float* Zp = ws + Z_OFF + (size_t)n * L * MN;
    #pragma unroll
    for (int a = 0; a < 4; ++a) {
        #pragma unroll
        for (int r = 0; r < 4; ++r) {
            int p = (pt0 + a) * 16 + qd * 4 + r;
            #pragma unroll
            for (int bq = 0; bq < 4; ++bq) {
                int m = (mt0 + bq) * 16 + fr;
                Zp[(size_t)p * MN + m] = acc[a][bq][r];
            }
        }
    }
}

// ---------------------------------------------------------------------------
// K7: gather epilogue, 2 c-planes per block.  Grid (8,16,48).
__global__ __launch_bounds__(256) void k7_gather(const float* __restrict__ ws,
                                                 float* __restrict__ out) {
    int n = blockIdx.x, yq = blockIdx.y, c0 = blockIdx.z * 2;
    int t = threadIdx.x;
    int y0 = yq * 4;
    int ibase = (y0 >> 1) - 1;
    __shared__ float zs[128][33];
    const float* Zp = ws + Z_OFF + (size_t)n * L * MN;
    #pragma unroll
    for (int e = 0; e < 4; ++e) {
        int idx = t + e * 256;          // 1024 = 128 pl x 8 float4-chunks
        int pl = idx >> 3, q = idx & 7;
        int il = pl >> 5, j = pl & 31;
        int i = ibase + il;
        float4 v = make_float4(0.f, 0.f, 0.f, 0.f);
        if (i >= 0 && i < HS)
            v = *(const float4*)&Zp[(size_t)(i * HS + j) * MN + c0 * 16 + q * 4];
        zs[pl][q * 4 + 0] = v.x;
        zs[pl][q * 4 + 1] = v.y;
        zs[pl][q * 4 + 2] = v.z;
        zs[pl][q * 4 + 3] = v.w;
    }
    __syncthreads();
    int y = y0 + (t >> 6), x = t & 63;
    int ih = (y + 1) >> 1, jh = (x + 1) >> 1;
    float s0 = 0.f, s1 = 0.f;
    #pragma unroll
    for (int di = 0; di < 2; ++di) {
        int i = ih - di;
        if (i < 0 || i >= HS) continue;
        int u = y + 1 - 2 * i;
        int il = i - ibase;
        #pragma unroll
        for (int dj = 0; dj < 2; ++dj) {
            int j = jh - dj;
            if (j < 0 || j >= HS) continue;
            int v = x + 1 - 2 * j;
            s0 += zs[il * 32 + j][u * 4 + v];
            s1 += zs[il * 32 + j][16 + u * 4 + v];
        }
    }
    out[(((size_t)n * NC + c0) * HF + y) * HF + x] = 0.25f * s0;
    out[(((size_t)n * NC + c0 + 1) * HF + y) * HF + x] = 0.25f * s1;
}

// ---------------------------------------------------------------------------
extern "C" void kernel_launch(void* const* d_in, const int* in_sizes, int n_in,
                              void* d_out, int out_size, void* d_ws, size_t ws_size,
                              hipStream_t stream) {
    const float* f = (const float*)d_in[0];
    const float* b = (const float*)d_in[1];
    float* out = (float*)d_out;
    float* ws = (float*)d_ws;

    kprep<<<dim3(NB, NC, 2), 256, 0, stream>>>(f, b, ws);
    k1_gram<<<dim3(NB, 9, 8), 256, 0, stream>>>(ws);
    k23_score_fuse1t<<<4096, 256, 0, stream>>>(ws);
    k4_fuse2_softmax<<<dim3(NB, 32, 8), 256, 0, stream>>>(ws);
    k6_mfma_z<<<dim3(NB, 12, 8), 256, 0, stream>>>(ws);
    k7_gather<<<dim3(NB, 16, 48), 256, 0, stream>>>(ws, out);
}